// Round 5
// baseline (263.544 us; speedup 1.0000x reference)
//
#include <hip/hip_runtime.h>

// Problem constants (B,C,H,W fixed by the reference setup)
#define B_   8
#define C_   10
#define H_   128
#define W_   128
#define HWSZ (H_ * W_)    // 16384
#define CHW  (C_ * HWSZ)  // 163840

#define TS   16           // spatial tile (16x16 outputs per block)
#define HL   18           // halo extent (TS + 2)
#define HSZ  (HL * HL)    // 324 halo pixels
#define NT   128          // 2 horizontal pixels per thread

__device__ __forceinline__ float sigm(float x)  { return 1.0f / (1.0f + __expf(-x)); }
__device__ __forceinline__ float tanh_(float x) { return 1.0f - 2.0f / (__expf(2.0f * x) + 1.0f); }
// compile-time component select (folds to .x/.y/.z/.w under full unroll)
__device__ __forceinline__ float comp(const float4 v, int c) {
    return c == 0 ? v.x : (c == 1 ? v.y : (c == 2 ? v.z : v.w));
}

// Single fused kernel. Weights staged to LDS (in-kernel, BN pre-folded),
// read back as float4 broadcasts (ds_read_b128). 2 px/thread halves
// per-pixel weight DS traffic; GRU weight rows read once per pixel-pair.
__global__ __launch_bounds__(NT) void fused_graph_kernel(
    const float* __restrict__ f_g,
    const float* __restrict__ h0_g,
    const float* __restrict__ h1_g,
    const float* __restrict__ attw_g,
    const float* __restrict__ attb_g,
    const float* __restrict__ relw_g,
    const float* __restrict__ gamma_g,
    const float* __restrict__ beta_g,
    const float* __restrict__ mean_g,
    const float* __restrict__ var_g,
    const float* __restrict__ gw_g,
    const float* __restrict__ gb_g,
    const float* __restrict__ cw_g,
    const float* __restrict__ cb_g,
    float* __restrict__ out_f,
    float* __restrict__ out_att)
{
    // LDS budget: 51840 + 4320*2 + 1600 + 960 + 160 = 63.2 KB -> 2 blocks/CU
    __shared__ float4 sIn[C_][HSZ];    // (f, h0*att, h1*att, att) per channel/pixel
    __shared__ float4 sWf[90 * 3];     // conv f-weights,  [(tap*10+ci)] x 12 floats (10 used), BN-scaled
    __shared__ float4 sWa[90 * 3];     // conv att-weights, same layout, BN-scaled
    __shared__ float4 sGW[100];        // gates  [in=20][20 floats]
    __shared__ float4 sCW[60];         // cand   [in=20][12 floats (10 used)]
    __shared__ float  sGB[20], sCB[10], sBi[10];

    const int tid = threadIdx.x;
    const int bx = blockIdx.x, by = blockIdx.y, b = blockIdx.z;

    // ---- weight staging: fold BN scale into conv weights; transpose for b128 reads ----
    float* sWfF = (float*)sWf;
    float* sWaF = (float*)sWa;
    for (int i = tid; i < 1800; i += NT) {
        const int tap = i / 200, r = i - tap * 200, ci = r / 20, j = r - ci * 20;
        const int c   = (j < 10) ? j : j - 10;           // output channel
        const int cin = (j < 10) ? ci : 10 + ci;         // input channel in rel_w
        const float sc = gamma_g[c] * rsqrtf(var_g[c] + 1e-5f);
        const float v = relw_g[(c * 20 + cin) * 9 + tap] * sc;
        if (j < 10) sWfF[(tap * 10 + ci) * 12 + c] = v;
        else        sWaF[(tap * 10 + ci) * 12 + c] = v;
    }
    float* sGWF = (float*)sGW;
    for (int i = tid; i < 400; i += NT) {                // [in][out] transpose
        const int in_c = i / 20, o = i - in_c * 20;
        sGWF[in_c * 20 + o] = gw_g[o * 20 + in_c];
    }
    float* sCWF = (float*)sCW;
    for (int i = tid; i < 200; i += NT) {                // [in][c] transpose (pad 10->12)
        const int in_c = i / 10, c = i - in_c * 10;
        sCWF[in_c * 12 + c] = cw_g[c * 20 + in_c];
    }
    if (tid < 20) sGB[tid] = gb_g[tid];
    if (tid < 10) {
        sCB[tid] = cb_g[tid];
        const float sc = gamma_g[tid] * rsqrtf(var_g[tid] + 1e-5f);
        sBi[tid] = beta_g[tid] - mean_g[tid] * sc;       // BN folded bias
    }

    // attention 1x1 weights (uniform)
    float aw[20];
    #pragma unroll
    for (int i = 0; i < 20; i++) aw[i] = attw_g[i];
    const float ab = attb_g[0];

    // ---- input halo staging; compute att per halo pixel once ----
    const int gy0 = by * TS - 1, gx0 = bx * TS - 1;
    for (int p = tid; p < HSZ; p += NT) {
        const int hy = p / HL, hx = p - hy * HL;
        const int gy = gy0 + hy, gx = gx0 + hx;
        if (gy >= 0 && gy < H_ && gx >= 0 && gx < W_) {
            const int base = b * CHW + gy * W_ + gx;
            float fv[10], h0v[10], h1v[10];
            float acc = ab;
            #pragma unroll
            for (int ci = 0; ci < 10; ci++) {
                fv[ci]  = f_g [base + ci * HWSZ];
                h0v[ci] = h0_g[base + ci * HWSZ];
                h1v[ci] = h1_g[base + ci * HWSZ];
                acc += aw[ci] * h0v[ci] + aw[10 + ci] * h1v[ci];
            }
            const float att = sigm(acc);
            #pragma unroll
            for (int ci = 0; ci < 10; ci++)
                sIn[ci][p] = make_float4(fv[ci], h0v[ci] * att, h1v[ci] * att, att);
        } else {  // zero padding (conv pad=1)
            #pragma unroll
            for (int ci = 0; ci < 10; ci++)
                sIn[ci][p] = make_float4(0.f, 0.f, 0.f, 0.f);
        }
    }
    __syncthreads();

    // ---- 3x3 conv: f-part shared between relations; 2 adjacent px/thread ----
    const int ly = tid >> 3, lx = tid & 7;               // 16 rows x 8 col-pairs
    const int hc = (ly + 1) * HL + (2 * lx + 1);         // halo index of pixel 0

    float accf[2][10], acc0[2][10], acc1[2][10];
    #pragma unroll
    for (int c = 0; c < 10; c++) {
        accf[0][c] = 0.f; accf[1][c] = 0.f;
        acc0[0][c] = 0.f; acc0[1][c] = 0.f;
        acc1[0][c] = 0.f; acc1[1][c] = 0.f;
    }

    #pragma unroll 1  // keep 9-tap loop rolled: ~large body, fits icache
    for (int tap = 0; tap < 9; tap++) {
        const int hi = hc + (tap / 3 - 1) * HL + (tap - (tap / 3) * 3 - 1);
        #pragma unroll
        for (int ci = 0; ci < 10; ci++) {
            const int wb = (tap * 10 + ci) * 3;
            const float4 wf0 = sWf[wb], wf1 = sWf[wb + 1], wf2 = sWf[wb + 2];
            const float4 wa0 = sWa[wb], wa1 = sWa[wb + 1], wa2 = sWa[wb + 2];
            const float4 v0 = sIn[ci][hi];
            const float4 v1 = sIn[ci][hi + 1];
            #pragma unroll
            for (int c = 0; c < 10; c++) {
                const float4 wfq = (c < 4) ? wf0 : (c < 8 ? wf1 : wf2);
                const float4 waq = (c < 4) ? wa0 : (c < 8 ? wa1 : wa2);
                const float wfv = comp(wfq, c & 3);
                const float wav = comp(waq, c & 3);
                accf[0][c] += wfv * v0.x; accf[1][c] += wfv * v1.x;
                acc0[0][c] += wav * v0.y; acc0[1][c] += wav * v1.y;
                acc1[0][c] += wav * v0.z; acc1[1][c] += wav * v1.z;
            }
        }
    }

    // ---- BN(folded) + ReLU + sum -> comp_h; fetch f center values ----
    float ch[2][10], fc[2][10];
    float att0, att1;
    {
        const float4 c0 = sIn[0][hc], c1 = sIn[0][hc + 1];
        fc[0][0] = c0.x; fc[1][0] = c1.x; att0 = c0.w; att1 = c1.w;
    }
    #pragma unroll
    for (int c = 1; c < 10; c++) {
        fc[0][c] = sIn[c][hc].x;
        fc[1][c] = sIn[c][hc + 1].x;
    }
    #pragma unroll
    for (int c = 0; c < 10; c++) {
        const float bi = sBi[c];
        ch[0][c] = fmaxf(accf[0][c] + acc0[0][c] + bi, 0.f)
                 + fmaxf(accf[0][c] + acc1[0][c] + bi, 0.f);
        ch[1][c] = fmaxf(accf[1][c] + acc0[1][c] + bi, 0.f)
                 + fmaxf(accf[1][c] + acc1[1][c] + bi, 0.f);
    }

    // ---- ConvGRU (1x1): weight rows read once (b128), used for both px ----
    float g[2][20];
    #pragma unroll
    for (int o = 0; o < 20; o++) { g[0][o] = sGB[o]; g[1][o] = sGB[o]; }
    #pragma unroll
    for (int i = 0; i < 10; i++) {
        const float4 r0a = sGW[i * 5],        r0b = sGW[i * 5 + 1],
                     r0c = sGW[i * 5 + 2],    r0d = sGW[i * 5 + 3],  r0e = sGW[i * 5 + 4];
        const float4 r1a = sGW[(10+i) * 5],   r1b = sGW[(10+i) * 5 + 1],
                     r1c = sGW[(10+i) * 5 + 2], r1d = sGW[(10+i) * 5 + 3], r1e = sGW[(10+i) * 5 + 4];
        #pragma unroll
        for (int o = 0; o < 20; o++) {
            const float4 w0 = (o < 4) ? r0a : (o < 8 ? r0b : (o < 12 ? r0c : (o < 16 ? r0d : r0e)));
            const float4 w1 = (o < 4) ? r1a : (o < 8 ? r1b : (o < 12 ? r1c : (o < 16 ? r1d : r1e)));
            const float wc = comp(w0, o & 3), wfv = comp(w1, o & 3);
            g[0][o] += ch[0][i] * wc + fc[0][i] * wfv;
            g[1][o] += ch[1][i] * wc + fc[1][i] * wfv;
        }
    }
    float cd[2][10];
    #pragma unroll
    for (int c = 0; c < 10; c++) { cd[0][c] = sCB[c]; cd[1][c] = sCB[c]; }
    #pragma unroll
    for (int i = 0; i < 10; i++) {
        const float4 r0a = sCW[i * 3],      r0b = sCW[i * 3 + 1],      r0c = sCW[i * 3 + 2];
        const float4 r1a = sCW[(10+i) * 3], r1b = sCW[(10+i) * 3 + 1], r1c = sCW[(10+i) * 3 + 2];
        const float rf0 = sigm(g[0][i]) * fc[0][i];   // reset * f
        const float rf1 = sigm(g[1][i]) * fc[1][i];
        #pragma unroll
        for (int c = 0; c < 10; c++) {
            const float4 w0 = (c < 4) ? r0a : (c < 8 ? r0b : r0c);
            const float4 w1 = (c < 4) ? r1a : (c < 8 ? r1b : r1c);
            const float wc = comp(w0, c & 3), wr = comp(w1, c & 3);
            cd[0][c] += ch[0][i] * wc + rf0 * wr;
            cd[1][c] += ch[1][i] * wc + rf1 * wr;
        }
    }

    // ---- packed float2 stores (gx even -> 8B aligned) ----
    const int gy = by * TS + ly, gx = bx * TS + 2 * lx;
    #pragma unroll
    for (int c = 0; c < 10; c++) {
        const float u0 = sigm(g[0][10 + c]);
        const float u1 = sigm(g[1][10 + c]);
        float2 v = make_float2((1.f - u0) * fc[0][c] + u0 * tanh_(cd[0][c]),
                               (1.f - u1) * fc[1][c] + u1 * tanh_(cd[1][c]));
        *reinterpret_cast<float2*>(&out_f[((b * C_ + c) * H_ + gy) * W_ + gx]) = v;
    }
    *reinterpret_cast<float2*>(&out_att[(b * H_ + gy) * W_ + gx]) = make_float2(att0, att1);
}

extern "C" void kernel_launch(void* const* d_in, const int* in_sizes, int n_in,
                              void* d_out, int out_size, void* d_ws, size_t ws_size,
                              hipStream_t stream) {
    (void)in_sizes; (void)n_in; (void)d_ws; (void)ws_size; (void)out_size;
    const float* f   = (const float*)d_in[0];
    const float* h0  = (const float*)d_in[1];
    const float* h1  = (const float*)d_in[2];
    // d_in[3] = p_nodes, d_in[4] = xf: unused by the reference -> never read
    const float* aw  = (const float*)d_in[5];
    const float* ab  = (const float*)d_in[6];
    const float* rw  = (const float*)d_in[7];
    const float* gam = (const float*)d_in[8];
    const float* bet = (const float*)d_in[9];
    const float* mea = (const float*)d_in[10];
    const float* var = (const float*)d_in[11];
    const float* gw  = (const float*)d_in[12];
    const float* gb  = (const float*)d_in[13];
    const float* cw  = (const float*)d_in[14];
    const float* cb  = (const float*)d_in[15];

    float* out_f   = (float*)d_out;
    float* out_att = out_f + (B_ * C_ * H_ * W_);

    dim3 grid(W_ / TS, H_ / TS, B_);
    fused_graph_kernel<<<grid, dim3(NT), 0, stream>>>(
        f, h0, h1, aw, ab, rw, gam, bet, mea, var, gw, gb, cw, cb, out_f, out_att);
}

// Round 6
// 252.151 us; speedup vs baseline: 1.0452x; 1.0452x over previous
//
#include <hip/hip_runtime.h>

// Problem constants (B,C,H,W fixed by the reference setup)
#define B_   8
#define C_   10
#define H_   128
#define W_   128
#define HWSZ (H_ * W_)    // 16384
#define CHW  (C_ * HWSZ)  // 163840

#define TS   16           // spatial tile (16x16 outputs per block)
#define HL   18           // halo extent (TS + 2)
#define HSZ  (HL * HL)    // 324 halo pixels
#define NT   256          // 1 pixel per thread (low VGPR pressure -- R5's 2px spilled)

__device__ __forceinline__ float sigm(float x)  { return 1.0f / (1.0f + __expf(-x)); }
__device__ __forceinline__ float tanh_(float x) { return 1.0f - 2.0f / (__expf(2.0f * x) + 1.0f); }

// Single fused kernel, R3 structure + in-kernel weight staging (no prep launch).
// Weights in LDS as float2 pairs -> one ds_read_b64 broadcast per 3 FMAs.
__global__ __launch_bounds__(NT) void fused_graph_kernel(
    const float* __restrict__ f_g,
    const float* __restrict__ h0_g,
    const float* __restrict__ h1_g,
    const float* __restrict__ attw_g,
    const float* __restrict__ attb_g,
    const float* __restrict__ relw_g,
    const float* __restrict__ gamma_g,
    const float* __restrict__ beta_g,
    const float* __restrict__ mean_g,
    const float* __restrict__ var_g,
    const float* __restrict__ gw_g,
    const float* __restrict__ gb_g,
    const float* __restrict__ cw_g,
    const float* __restrict__ cb_g,
    float* __restrict__ out_f,
    float* __restrict__ out_att)
{
    // LDS: 51840 (sIn) + 7200 (sWc) + 1600 (sGWp) + 800 (sCWp) + 160 = 61.6 KB -> 2 blocks/CU
    __shared__ float4 sIn[C_][HSZ];     // (f, h0*att, h1*att, att) per channel/pixel
    __shared__ float2 sWc[900];         // conv: [(tap*10+ci)*10 + c] = (wf*sc, wa*sc)
    __shared__ float2 sGWp[200];        // gates: [i*20 + o] = (W[ch_i][o], W[f_i][o])
    __shared__ float2 sCWp[100];        // cand:  [i*10 + c] = (W[c][ch_i], W[c][f_i])
    __shared__ float  sGB[20], sCB[10], sBi[10];

    const int tid = threadIdx.x;
    const int bx = blockIdx.x, by = blockIdx.y, b = blockIdx.z;

    // ---- weight staging (BN scale folded into conv weights) ----
    float* sWcF = (float*)sWc;
    for (int i = tid; i < 1800; i += NT) {
        const int pair = i >> 1, part = i & 1;           // part: 0=f-weight, 1=att-weight
        const int tap = pair / 100, r = pair - tap * 100, ci = r / 10, c = r - ci * 10;
        const int cin = part ? (10 + ci) : ci;
        const float sc = gamma_g[c] * rsqrtf(var_g[c] + 1e-5f);
        // rel_w layout: [c_out=10][cin=20][ky*3+kx]
        sWcF[(tap * 100 + ci * 10 + c) * 2 + part] = relw_g[(c * 20 + cin) * 9 + tap] * sc;
    }
    float* sGWpF = (float*)sGWp;
    for (int i = tid; i < 400; i += NT) {
        const int pair = i >> 1, part = i & 1;           // part: 0=ch input, 1=f input
        const int i10 = pair / 20, o = pair - i10 * 20;
        sGWpF[i] = gw_g[o * 20 + part * 10 + i10];       // gates_w [o=20][in=20]
    }
    float* sCWpF = (float*)sCWp;
    for (int i = tid; i < 200; i += NT) {
        const int pair = i >> 1, part = i & 1;           // part: 0=ch input, 1=reset*f input
        const int i10 = pair / 10, c = pair - i10 * 10;
        sCWpF[i] = cw_g[c * 20 + part * 10 + i10];       // can_w [c=10][in=20]
    }
    if (tid < 20) sGB[tid] = gb_g[tid];
    if (tid < 10) {
        sCB[tid] = cb_g[tid];
        const float sc = gamma_g[tid] * rsqrtf(var_g[tid] + 1e-5f);
        sBi[tid] = beta_g[tid] - mean_g[tid] * sc;       // BN folded bias
    }

    // attention 1x1 weights (uniform)
    float aw[20];
    #pragma unroll
    for (int i = 0; i < 20; i++) aw[i] = attw_g[i];
    const float ab = attb_g[0];

    // ---- input halo staging; compute att per halo pixel once ----
    const int gy0 = by * TS - 1, gx0 = bx * TS - 1;
    for (int p = tid; p < HSZ; p += NT) {
        const int hy = p / HL, hx = p - hy * HL;
        const int gy = gy0 + hy, gx = gx0 + hx;
        if (gy >= 0 && gy < H_ && gx >= 0 && gx < W_) {
            const int base = b * CHW + gy * W_ + gx;
            float fv[10], h0v[10], h1v[10];
            float acc = ab;
            #pragma unroll
            for (int ci = 0; ci < 10; ci++) {
                fv[ci]  = f_g [base + ci * HWSZ];
                h0v[ci] = h0_g[base + ci * HWSZ];
                h1v[ci] = h1_g[base + ci * HWSZ];
                acc += aw[ci] * h0v[ci] + aw[10 + ci] * h1v[ci];
            }
            const float att = sigm(acc);
            #pragma unroll
            for (int ci = 0; ci < 10; ci++)
                sIn[ci][p] = make_float4(fv[ci], h0v[ci] * att, h1v[ci] * att, att);
        } else {  // zero padding (conv pad=1)
            #pragma unroll
            for (int ci = 0; ci < 10; ci++)
                sIn[ci][p] = make_float4(0.f, 0.f, 0.f, 0.f);
        }
    }
    __syncthreads();

    // ---- 3x3 conv: f-part shared between both relations; 1 pixel/thread ----
    const int ly = tid >> 4, lx = tid & 15;
    const int hc = (ly + 1) * HL + (lx + 1);

    float accf[10], acc0[10], acc1[10];
    #pragma unroll
    for (int c = 0; c < 10; c++) { accf[c] = 0.f; acc0[c] = 0.f; acc1[c] = 0.f; }

    #pragma unroll 1  // keep 9-tap loop rolled (icache)
    for (int tap = 0; tap < 9; tap++) {
        const int hi = hc + (tap / 3 - 1) * HL + (tap - (tap / 3) * 3 - 1);
        #pragma unroll
        for (int ci = 0; ci < 10; ci++) {
            const float4 v = sIn[ci][hi];                // one ds_read_b128
            const int wb = tap * 100 + ci * 10;
            #pragma unroll
            for (int c = 0; c < 10; c++) {
                const float2 w = sWc[wb + c];            // one ds_read_b64 broadcast
                accf[c] += w.x * v.x;
                acc0[c] += w.y * v.y;
                acc1[c] += w.y * v.z;
            }
        }
    }

    // ---- BN(folded) + ReLU + sum -> comp_h; fetch f center values ----
    float ch[10], fc[10], attv;
    {
        const float4 cv = sIn[0][hc];
        fc[0] = cv.x; attv = cv.w;
    }
    #pragma unroll
    for (int c = 1; c < 10; c++) fc[c] = sIn[c][hc].x;
    #pragma unroll
    for (int c = 0; c < 10; c++) {
        const float bi = sBi[c];
        ch[c] = fmaxf(accf[c] + acc0[c] + bi, 0.f)
              + fmaxf(accf[c] + acc1[c] + bi, 0.f);
    }

    // ---- ConvGRU (1x1): paired ds_read_b64 weights ----
    float g[20];
    #pragma unroll
    for (int o = 0; o < 20; o++) g[o] = sGB[o];
    #pragma unroll
    for (int i = 0; i < 10; i++) {
        #pragma unroll
        for (int o = 0; o < 20; o++) {
            const float2 w = sGWp[i * 20 + o];
            g[o] += ch[i] * w.x + fc[i] * w.y;
        }
    }
    float cd[10];
    #pragma unroll
    for (int c = 0; c < 10; c++) cd[c] = sCB[c];
    #pragma unroll
    for (int i = 0; i < 10; i++) {
        const float rf = sigm(g[i]) * fc[i];   // reset * f
        #pragma unroll
        for (int c = 0; c < 10; c++) {
            const float2 w = sCWp[i * 10 + c];
            cd[c] += ch[i] * w.x + rf * w.y;
        }
    }

    const int gy = by * TS + ly, gx = bx * TS + lx;
    #pragma unroll
    for (int c = 0; c < 10; c++) {
        const float u = sigm(g[10 + c]);       // update gate
        out_f[((b * C_ + c) * H_ + gy) * W_ + gx] = (1.f - u) * fc[c] + u * tanh_(cd[c]);
    }
    out_att[(b * H_ + gy) * W_ + gx] = attv;
}

extern "C" void kernel_launch(void* const* d_in, const int* in_sizes, int n_in,
                              void* d_out, int out_size, void* d_ws, size_t ws_size,
                              hipStream_t stream) {
    (void)in_sizes; (void)n_in; (void)d_ws; (void)ws_size; (void)out_size;
    const float* f   = (const float*)d_in[0];
    const float* h0  = (const float*)d_in[1];
    const float* h1  = (const float*)d_in[2];
    // d_in[3] = p_nodes, d_in[4] = xf: unused by the reference -> never read
    const float* aw  = (const float*)d_in[5];
    const float* ab  = (const float*)d_in[6];
    const float* rw  = (const float*)d_in[7];
    const float* gam = (const float*)d_in[8];
    const float* bet = (const float*)d_in[9];
    const float* mea = (const float*)d_in[10];
    const float* var = (const float*)d_in[11];
    const float* gw  = (const float*)d_in[12];
    const float* gb  = (const float*)d_in[13];
    const float* cw  = (const float*)d_in[14];
    const float* cb  = (const float*)d_in[15];

    float* out_f   = (float*)d_out;
    float* out_att = out_f + (B_ * C_ * H_ * W_);

    dim3 grid(W_ / TS, H_ / TS, B_);
    fused_graph_kernel<<<grid, dim3(NT), 0, stream>>>(
        f, h0, h1, aw, ab, rw, gam, bet, mea, var, gw, gb, cw, cb, out_f, out_att);
}